// Round 1
// baseline (1091.177 us; speedup 1.0000x reference)
//
#include <hip/hip_runtime.h>
#include <hip/hip_bf16.h>
#include <math.h>

typedef __hip_bfloat16 bf16;
using bf16x8 = __bf16 __attribute__((ext_vector_type(8)));
using f32x4  = float  __attribute__((ext_vector_type(4)));

#define D_MODEL 2048
#define S_LEN   2048
#define NB      2
#define NH      16
#define DHEAD   128
#define DFF     8192
#define M_ROWS  (NB * S_LEN)   // 4096

// ---------------------------------------------------------------------------
// LayerNorm: fp32 [rows][2048] -> bf16 [rows][2048], one block per row
// ---------------------------------------------------------------------------
__global__ __launch_bounds__(256) void ln_kernel(const float* __restrict__ x,
                                                 const float* __restrict__ gw,
                                                 const float* __restrict__ bw,
                                                 bf16* __restrict__ out) {
    const int row = blockIdx.x;
    const float* xr = x + (size_t)row * D_MODEL;
    const int tid = threadIdx.x;
    float4 v0 = ((const float4*)xr)[tid * 2];
    float4 v1 = ((const float4*)xr)[tid * 2 + 1];
    float s = v0.x + v0.y + v0.z + v0.w + v1.x + v1.y + v1.z + v1.w;
    float q = v0.x*v0.x + v0.y*v0.y + v0.z*v0.z + v0.w*v0.w
            + v1.x*v1.x + v1.y*v1.y + v1.z*v1.z + v1.w*v1.w;
    #pragma unroll
    for (int off = 32; off; off >>= 1) {
        s += __shfl_xor(s, off);
        q += __shfl_xor(q, off);
    }
    __shared__ float red[8];
    const int wid = tid >> 6;
    if ((tid & 63) == 0) { red[wid] = s; red[4 + wid] = q; }
    __syncthreads();
    s = red[0] + red[1] + red[2] + red[3];
    q = red[4] + red[5] + red[6] + red[7];
    const float mean = s * (1.0f / D_MODEL);
    const float var  = q * (1.0f / D_MODEL) - mean * mean;
    const float inv  = rsqrtf(var + 1e-5f);
    float4 g0 = ((const float4*)gw)[tid * 2];
    float4 g1 = ((const float4*)gw)[tid * 2 + 1];
    float4 b0 = ((const float4*)bw)[tid * 2];
    float4 b1 = ((const float4*)bw)[tid * 2 + 1];
    bf16* orow = out + (size_t)row * D_MODEL + tid * 8;
    orow[0] = __float2bfloat16((v0.x - mean) * inv * g0.x + b0.x);
    orow[1] = __float2bfloat16((v0.y - mean) * inv * g0.y + b0.y);
    orow[2] = __float2bfloat16((v0.z - mean) * inv * g0.z + b0.z);
    orow[3] = __float2bfloat16((v0.w - mean) * inv * g0.w + b0.w);
    orow[4] = __float2bfloat16((v1.x - mean) * inv * g1.x + b1.x);
    orow[5] = __float2bfloat16((v1.y - mean) * inv * g1.y + b1.y);
    orow[6] = __float2bfloat16((v1.z - mean) * inv * g1.z + b1.z);
    orow[7] = __float2bfloat16((v1.w - mean) * inv * g1.w + b1.w);
}

// ---------------------------------------------------------------------------
// Transpose+convert: fp32 [R][C] -> bf16 [C][R]  (weights -> W^T bf16)
// ---------------------------------------------------------------------------
__global__ __launch_bounds__(256) void transpose_f2b(const float* __restrict__ in,
                                                     bf16* __restrict__ out,
                                                     int R, int C) {
    __shared__ float t[32][33];
    const int c0 = blockIdx.x * 32, r0 = blockIdx.y * 32;
    const int tx = threadIdx.x & 31, ty = threadIdx.x >> 5;
    #pragma unroll
    for (int i = ty; i < 32; i += 8) t[i][tx] = in[(size_t)(r0 + i) * C + c0 + tx];
    __syncthreads();
    #pragma unroll
    for (int i = ty; i < 32; i += 8)
        out[(size_t)(c0 + i) * R + r0 + tx] = __float2bfloat16(t[tx][i]);
}

// Per-head V transpose: bf16 [S][128] -> bf16 [128][S] (32 heads via blockIdx.z)
__global__ __launch_bounds__(256) void transpose_v(const bf16* __restrict__ in,
                                                   bf16* __restrict__ out) {
    const int bh = blockIdx.z;
    const bf16* ib = in + (size_t)bh * S_LEN * DHEAD;
    bf16* ob = out + (size_t)bh * DHEAD * S_LEN;
    __shared__ float t[32][33];
    const int c0 = blockIdx.x * 32;   // over DHEAD
    const int r0 = blockIdx.y * 32;   // over S
    const int tx = threadIdx.x & 31, ty = threadIdx.x >> 5;
    #pragma unroll
    for (int i = ty; i < 32; i += 8)
        t[i][tx] = __bfloat162float(ib[(size_t)(r0 + i) * DHEAD + c0 + tx]);
    __syncthreads();
    #pragma unroll
    for (int i = ty; i < 32; i += 8)
        ob[(size_t)(c0 + i) * S_LEN + r0 + tx] = __float2bfloat16(t[tx][i]);
}

// ---------------------------------------------------------------------------
// In-place RoPE on q,k: qkv layout [which][B*H][S][128], which in {0,1}
// ---------------------------------------------------------------------------
__global__ __launch_bounds__(256) void rope_kernel(bf16* __restrict__ qk,
                                                   const float* __restrict__ ct,
                                                   const float* __restrict__ st) {
    const size_t idx = (size_t)blockIdx.x * 256 + threadIdx.x;  // 2*32*2048*64
    const int dh = (int)(idx & 63);
    const size_t rrow = idx >> 6;
    const int sidx = (int)(rrow & (S_LEN - 1));
    bf16* p = qk + rrow * DHEAD;
    const float c  = ct[sidx * DHEAD + dh];
    const float sn = st[sidx * DHEAD + dh];
    const float x1 = __bfloat162float(p[dh]);
    const float x2 = __bfloat162float(p[dh + 64]);
    p[dh]      = __float2bfloat16(x1 * c - x2 * sn);
    p[dh + 64] = __float2bfloat16(x2 * c + x1 * sn);
}

// ---------------------------------------------------------------------------
// GEMM: C[M][N] = A[M][K] (bf16) @ Bt[N][K]^T (bf16) + bias, fused epilogues.
// 128x128 tile, BK=64, 4 waves (2x2), 4x4 16x16x32 frags per wave.
// EPI 0: scatter bf16 to qkv [3][32][S][128]
// EPI 1: fp32 out = acc + bias + resid
// EPI 2: bf16 out = gelu_exact(acc + bias)
// ---------------------------------------------------------------------------
template <int EPI>
__global__ __launch_bounds__(256) void gemm_kernel(const bf16* __restrict__ A,
                                                   const bf16* __restrict__ Bt,
                                                   const float* __restrict__ bias,
                                                   const float* __restrict__ resid,
                                                   void* __restrict__ outp,
                                                   int M, int N, int K) {
    __shared__ __align__(16) bf16 As[128][72];
    __shared__ __align__(16) bf16 Bs[128][72];
    const int tid  = threadIdx.x;
    const int lane = tid & 63;
    const int wid  = tid >> 6;
    const int wr = wid >> 1, wc = wid & 1;
    const int cc = lane & 15, g = lane >> 4;
    const int m0 = blockIdx.y * 128, n0 = blockIdx.x * 128;

    f32x4 acc[4][4];
    const f32x4 zero = {0.f, 0.f, 0.f, 0.f};
    #pragma unroll
    for (int i = 0; i < 4; i++)
        #pragma unroll
        for (int j = 0; j < 4; j++) acc[i][j] = zero;

    for (int k0 = 0; k0 < K; k0 += 64) {
        #pragma unroll
        for (int i = 0; i < 4; ++i) {
            const int idx = tid + i * 256;       // 0..1023
            const int row = idx >> 3;            // 0..127
            const int ks  = (idx & 7) * 8;       // bf16 offset 0..56
            *(bf16x8*)(&As[row][ks]) = *(const bf16x8*)(A  + (size_t)(m0 + row) * K + k0 + ks);
            *(bf16x8*)(&Bs[row][ks]) = *(const bf16x8*)(Bt + (size_t)(n0 + row) * K + k0 + ks);
        }
        __syncthreads();
        #pragma unroll
        for (int kk = 0; kk < 64; kk += 32) {
            bf16x8 af[4], bfm[4];
            const int ko = kk + g * 8;
            #pragma unroll
            for (int mi = 0; mi < 4; mi++) af[mi]  = *(const bf16x8*)(&As[wr * 64 + mi * 16 + cc][ko]);
            #pragma unroll
            for (int ni = 0; ni < 4; ni++) bfm[ni] = *(const bf16x8*)(&Bs[wc * 64 + ni * 16 + cc][ko]);
            #pragma unroll
            for (int mi = 0; mi < 4; mi++)
                #pragma unroll
                for (int ni = 0; ni < 4; ni++)
                    acc[mi][ni] = __builtin_amdgcn_mfma_f32_16x16x32_bf16(af[mi], bfm[ni], acc[mi][ni], 0, 0, 0);
        }
        __syncthreads();
    }

    #pragma unroll
    for (int mi = 0; mi < 4; mi++) {
        #pragma unroll
        for (int ni = 0; ni < 4; ni++) {
            const int colb = n0 + wc * 64 + ni * 16 + cc;
            const float bcol = bias[colb];
            #pragma unroll
            for (int r = 0; r < 4; r++) {
                const int row = m0 + wr * 64 + mi * 16 + g * 4 + r;
                const float v = acc[mi][ni][r] + bcol;
                if (EPI == 0) {
                    const int which = colb >> 11;
                    const int h     = (colb >> 7) & 15;
                    const int dh    = colb & 127;
                    const int b     = row >> 11;
                    const int sidx  = row & (S_LEN - 1);
                    bf16* o = (bf16*)outp;
                    o[((size_t)(which * 32 + b * 16 + h) * S_LEN + sidx) * DHEAD + dh] = __float2bfloat16(v);
                } else if (EPI == 1) {
                    float* o = (float*)outp;
                    o[(size_t)row * N + colb] = v + resid[(size_t)row * N + colb];
                } else {
                    bf16* o = (bf16*)outp;
                    const float gel = 0.5f * v * (1.0f + erff(v * 0.70710678118f));
                    o[(size_t)row * N + colb] = __float2bfloat16(gel);
                }
            }
        }
    }
}

// ---------------------------------------------------------------------------
// Flash attention, causal. 1 wave per block, 16 q-rows, 32 kv per step.
// q,k: [32][S][128] bf16 (rope applied); vT: [32][128][S] bf16.
// out: aout [B][S][H*128] bf16.
// ---------------------------------------------------------------------------
__global__ __launch_bounds__(64) void attn_kernel(const bf16* __restrict__ q,
                                                  const bf16* __restrict__ k,
                                                  const bf16* __restrict__ vT,
                                                  bf16* __restrict__ aout) {
    const int bid = blockIdx.x;
    const int qt = bid & 127;     // S/16 q-tiles
    const int bh = bid >> 7;      // 0..31
    const int lane = threadIdx.x;
    const int cc = lane & 15, g = lane >> 4;
    const int q0 = qt * 16;
    const bf16* qb = q  + (size_t)bh * S_LEN * DHEAD;
    const bf16* kb = k  + (size_t)bh * S_LEN * DHEAD;
    const bf16* vb = vT + (size_t)bh * DHEAD * S_LEN;

    bf16x8 qf[4];
    #pragma unroll
    for (int kk = 0; kk < 4; kk++)
        qf[kk] = *(const bf16x8*)(qb + (size_t)(q0 + cc) * DHEAD + kk * 32 + g * 8);

    f32x4 oacc[8];
    const f32x4 zero = {0.f, 0.f, 0.f, 0.f};
    #pragma unroll
    for (int d = 0; d < 8; d++) oacc[d] = zero;
    float m_run[4] = {-1e30f, -1e30f, -1e30f, -1e30f};
    float l_run[4] = {0.f, 0.f, 0.f, 0.f};

    __shared__ __align__(16) bf16 Pt[16][40];
    const int ktmax = (q0 + 15) >> 5;
    const float scale = 0.08838834764831845f;   // 1/sqrt(128)

    for (int kt = 0; kt <= ktmax; ++kt) {
        const int kv0 = kt * 32;
        f32x4 sacc0 = zero, sacc1 = zero;
        #pragma unroll
        for (int kk = 0; kk < 4; kk++) {
            bf16x8 kf0 = *(const bf16x8*)(kb + (size_t)(kv0 + cc) * DHEAD + kk * 32 + g * 8);
            bf16x8 kf1 = *(const bf16x8*)(kb + (size_t)(kv0 + 16 + cc) * DHEAD + kk * 32 + g * 8);
            sacc0 = __builtin_amdgcn_mfma_f32_16x16x32_bf16(qf[kk], kf0, sacc0, 0, 0, 0);
            sacc1 = __builtin_amdgcn_mfma_f32_16x16x32_bf16(qf[kk], kf1, sacc1, 0, 0, 0);
        }
        float sc[2][4];
        #pragma unroll
        for (int r = 0; r < 4; r++) {
            const int qrow = q0 + g * 4 + r;
            sc[0][r] = (kv0 + cc      <= qrow) ? sacc0[r] * scale : -1e9f;
            sc[1][r] = (kv0 + 16 + cc <= qrow) ? sacc1[r] * scale : -1e9f;
        }
        float p0[4], p1[4], alpha[4];
        #pragma unroll
        for (int r = 0; r < 4; r++) {
            float mt = fmaxf(sc[0][r], sc[1][r]);
            #pragma unroll
            for (int off = 1; off < 16; off <<= 1) mt = fmaxf(mt, __shfl_xor(mt, off));
            const float mnew = fmaxf(m_run[r], mt);
            alpha[r] = expf(m_run[r] - mnew);
            m_run[r] = mnew;
            p0[r] = expf(sc[0][r] - mnew);
            p1[r] = expf(sc[1][r] - mnew);
            float rs = p0[r] + p1[r];
            #pragma unroll
            for (int off = 1; off < 16; off <<= 1) rs += __shfl_xor(rs, off);
            l_run[r] = l_run[r] * alpha[r] + rs;
        }
        #pragma unroll
        for (int d = 0; d < 8; d++) {
            f32x4 t = oacc[d];
            t[0] *= alpha[0]; t[1] *= alpha[1]; t[2] *= alpha[2]; t[3] *= alpha[3];
            oacc[d] = t;
        }
        #pragma unroll
        for (int r = 0; r < 4; r++) {
            Pt[g * 4 + r][cc]      = __float2bfloat16(p0[r]);
            Pt[g * 4 + r][16 + cc] = __float2bfloat16(p1[r]);
        }
        __syncthreads();
        const bf16x8 pf = *(const bf16x8*)(&Pt[cc][g * 8]);
        #pragma unroll
        for (int d = 0; d < 8; d++) {
            bf16x8 vf = *(const bf16x8*)(vb + (size_t)(d * 16 + cc) * S_LEN + kv0 + g * 8);
            oacc[d] = __builtin_amdgcn_mfma_f32_16x16x32_bf16(pf, vf, oacc[d], 0, 0, 0);
        }
        __syncthreads();
    }

    const int b = bh >> 4, h = bh & 15;
    #pragma unroll
    for (int r = 0; r < 4; r++) {
        const float invl = 1.0f / l_run[r];
        const int srow = q0 + g * 4 + r;
        bf16* orow = aout + ((size_t)(b * S_LEN + srow)) * D_MODEL + h * DHEAD;
        #pragma unroll
        for (int d = 0; d < 8; d++) orow[d * 16 + cc] = __float2bfloat16(oacc[d][r] * invl);
    }
}

// ---------------------------------------------------------------------------
extern "C" void kernel_launch(void* const* d_in, const int* in_sizes, int n_in,
                              void* d_out, int out_size, void* d_ws, size_t ws_size,
                              hipStream_t stream) {
    (void)in_sizes; (void)n_in; (void)out_size; (void)ws_size;
    const float* x      = (const float*)d_in[0];
    const float* cosb   = (const float*)d_in[1];
    const float* sinb   = (const float*)d_in[2];
    // d_in[3] = mask (causal, implemented directly)
    const float* ln1_g  = (const float*)d_in[4];
    const float* ln1_b  = (const float*)d_in[5];
    const float* w_qkv  = (const float*)d_in[6];
    const float* b_qkv  = (const float*)d_in[7];
    const float* w_out  = (const float*)d_in[8];
    const float* b_out  = (const float*)d_in[9];
    const float* ln2_g  = (const float*)d_in[10];
    const float* ln2_b  = (const float*)d_in[11];
    const float* w_ff1  = (const float*)d_in[12];
    const float* b_ff1  = (const float*)d_in[13];
    const float* w_ff2  = (const float*)d_in[14];
    const float* b_ff2  = (const float*)d_in[15];
    float* out = (float*)d_out;

    char* ws = (char*)d_ws;
    bf16* wT_qkv = (bf16*)(ws + 0);            // [6144][2048]  25,165,824 B
    bf16* wT_out = (bf16*)(ws + 25165824);     // [2048][2048]   8,388,608 B
    bf16* wT_ff1 = (bf16*)(ws + 33554432);     // [8192][2048]  33,554,432 B
    bf16* wT_ff2 = (bf16*)(ws + 67108864);     // [2048][8192]  33,554,432 B
    bf16* xn     = (bf16*)(ws + 100663296);    // [4096][2048]  16,777,216 B
    bf16* qkv    = (bf16*)(ws + 117440512);    // [3][32][2048][128] 50,331,648 B
    bf16* aoutb  = (bf16*)(ws + 167772160);    // [4096][2048]  16,777,216 B
    bf16* vTb    = (bf16*)(ws + 184549376);    // [32][128][2048] 16,777,216 B -> end 201,326,592
    bf16* hbuf   = (bf16*)(ws + 117440512);    // [4096][8192] aliases qkv+aout (both dead by FF1)
    bf16* kbuf = qkv + (size_t)32 * S_LEN * DHEAD;
    bf16* vbuf = qkv + (size_t)64 * S_LEN * DHEAD;

    // weights -> bf16 W^T
    transpose_f2b<<<dim3(192, 64),  256, 0, stream>>>(w_qkv, wT_qkv, 2048, 6144);
    transpose_f2b<<<dim3(64, 64),   256, 0, stream>>>(w_out, wT_out, 2048, 2048);
    transpose_f2b<<<dim3(256, 64),  256, 0, stream>>>(w_ff1, wT_ff1, 2048, 8192);
    transpose_f2b<<<dim3(64, 256),  256, 0, stream>>>(w_ff2, wT_ff2, 8192, 2048);

    // LN1 -> xn
    ln_kernel<<<M_ROWS, 256, 0, stream>>>(x, ln1_g, ln1_b, xn);
    // QKV GEMM with scatter epilogue
    gemm_kernel<0><<<dim3(48, 32), 256, 0, stream>>>(xn, wT_qkv, b_qkv, nullptr, qkv, M_ROWS, 6144, 2048);
    // RoPE in-place on q,k
    rope_kernel<<<32768, 256, 0, stream>>>(qkv, cosb, sinb);
    // V -> V^T per head
    transpose_v<<<dim3(4, 64, 32), 256, 0, stream>>>(vbuf, vTb);
    // attention
    attn_kernel<<<4096, 64, 0, stream>>>(qkv, kbuf, vTb, aoutb);
    // out-proj + residual(x) -> d_out (fp32 x2)
    gemm_kernel<1><<<dim3(16, 32), 256, 0, stream>>>(aoutb, wT_out, b_out, x, out, M_ROWS, 2048, 2048);
    // LN2 -> xn (reuse)
    ln_kernel<<<M_ROWS, 256, 0, stream>>>(out, ln2_g, ln2_b, xn);
    // FF1 + GELU -> h
    gemm_kernel<2><<<dim3(64, 32), 256, 0, stream>>>(xn, wT_ff1, b_ff1, nullptr, hbuf, M_ROWS, DFF, 2048);
    // FF2 + residual(d_out) -> d_out
    gemm_kernel<1><<<dim3(16, 32), 256, 0, stream>>>(hbuf, wT_ff2, b_ff2, out, out, M_ROWS, 2048, DFF);
}